// Round 1
// baseline (471.341 us; speedup 1.0000x reference)
//
#include <hip/hip_runtime.h>

#define S_LEN 2048
#define EMB 2048
#define NH 16
#define NKV 4
#define HD 128
#define WINDOW 1024
#define BATCH 2

typedef _Float16 half8 __attribute__((ext_vector_type(8)));
typedef _Float16 half4_t __attribute__((ext_vector_type(4)));
typedef _Float16 half2_t __attribute__((ext_vector_type(2)));
typedef float f32x4 __attribute__((ext_vector_type(4)));

#define MFMA16(a, b, c) __builtin_amdgcn_mfma_f32_16x16x32_f16((a), (b), (c), 0, 0, 0)

// ---------------------------------------------------------------------------
// Fused QKV projection: C = x @ W^T for W in {Wq, Wk, Wv}, selected by n-tile.
// A = x fp32 [4096, 2048]; W fp32 [N,2048]; outputs fp16.
// 128x128 tile, BK=64, 4 waves in 2x2, each wave 64x64 via 4x4 MFMA tiles.
// LDS rows padded 64->72 halves so ds_read_b128 frag reads are ~2-way (free).
// ---------------------------------------------------------------------------
__global__ __launch_bounds__(256)
void qkv_gemm(const float* __restrict__ x,
              const float* __restrict__ Wq, const float* __restrict__ Wk,
              const float* __restrict__ Wv,
              _Float16* __restrict__ Qh, _Float16* __restrict__ Kh16,
              _Float16* __restrict__ Vh16) {
  __shared__ _Float16 Asm[128 * 72];
  __shared__ _Float16 Bsm[128 * 72];
  const int K = EMB;
  int m0 = blockIdx.y * 128;
  int n0 = blockIdx.x * 128;
  const float* Wp; _Float16* Cp; int ncols, c0;
  if (n0 < 2048)      { Wp = Wq; Cp = Qh;   ncols = 2048; c0 = n0; }
  else if (n0 < 2560) { Wp = Wk; Cp = Kh16; ncols = 512;  c0 = n0 - 2048; }
  else                { Wp = Wv; Cp = Vh16; ncols = 512;  c0 = n0 - 2560; }

  int t = threadIdx.x;
  int lane = t & 63, w = t >> 6;
  int l15 = lane & 15, quad = lane >> 4;
  int wm = (w >> 1) * 64, wn = (w & 1) * 64;

  f32x4 acc[4][4] = {};

  int sr = t >> 4, sc = (t & 15) * 4;
  for (int kt = 0; kt < K; kt += 64) {
    __syncthreads();
#pragma unroll
    for (int p = 0; p < 8; ++p) {
      int row = p * 16 + sr;
      f32x4 va = *(const f32x4*)(x + (size_t)(m0 + row) * K + kt + sc);
      half4_t ha = { (_Float16)va[0], (_Float16)va[1], (_Float16)va[2], (_Float16)va[3] };
      *(half4_t*)&Asm[row * 72 + sc] = ha;
      f32x4 vb = *(const f32x4*)(Wp + (size_t)(c0 + row) * K + kt + sc);
      half4_t hb = { (_Float16)vb[0], (_Float16)vb[1], (_Float16)vb[2], (_Float16)vb[3] };
      *(half4_t*)&Bsm[row * 72 + sc] = hb;
    }
    __syncthreads();
#pragma unroll
    for (int kc = 0; kc < 2; ++kc) {
      half8 af[4], bf[4];
#pragma unroll
      for (int i = 0; i < 4; ++i)
        af[i] = *(const half8*)&Asm[(wm + i * 16 + l15) * 72 + kc * 32 + quad * 8];
#pragma unroll
      for (int i = 0; i < 4; ++i)
        bf[i] = *(const half8*)&Bsm[(wn + i * 16 + l15) * 72 + kc * 32 + quad * 8];
#pragma unroll
      for (int mi = 0; mi < 4; ++mi)
#pragma unroll
        for (int ni = 0; ni < 4; ++ni)
          acc[mi][ni] = MFMA16(af[mi], bf[ni], acc[mi][ni]);
    }
  }
#pragma unroll
  for (int mi = 0; mi < 4; ++mi)
#pragma unroll
    for (int ni = 0; ni < 4; ++ni)
#pragma unroll
      for (int r = 0; r < 4; ++r) {
        int row = m0 + wm + mi * 16 + quad * 4 + r;
        int col = c0 + wn + ni * 16 + l15;
        Cp[(size_t)row * ncols + col] = (_Float16)acc[mi][ni][r];
      }
}

// ---------------------------------------------------------------------------
// Flash attention with fused RoPE + GQA + sliding-window causal mask.
// One block per (q-tile of 64, head, batch). 4 waves; wave w owns 16 q rows.
// Q kept in registers as MFMA A-frags (RoPE applied in-register: partner
// element d+-64 is the same lane's kc^2 fragment). scale*log2e folded into Q
// so softmax uses exp2. K-tile roped during LDS staging. V staged into LDS in
// B-fragment order so PV B-frags are contiguous ds_read_b128.
// P goes C-layout -> LDS (padded) -> A-layout, per-wave private buffer.
// ---------------------------------------------------------------------------
__global__ __launch_bounds__(256)
void attn_fused(const _Float16* __restrict__ Qh, const _Float16* __restrict__ Kg,
                const _Float16* __restrict__ Vg, const float* __restrict__ cosT,
                const float* __restrict__ sinT, _Float16* __restrict__ Oh) {
  const float SL2E = 0.08838834764831843f * 1.4426950408889634f; // 1/sqrt(128) * log2(e)
  int qt = blockIdx.x, h = blockIdx.y, b = blockIdx.z;
  int kvh = h >> 2;
  int q0 = qt * 64;
  int t = threadIdx.x, lane = t & 63, w = t >> 6;
  int l15 = lane & 15, quad = lane >> 4;

  __shared__ _Float16 Ksm[64 * 136];      // roped K tile [key][d], pad 128->136
  __shared__ _Float16 Vsm[16 * 64 * 8];   // V tile in B-frag order [kc2*8+nc][lane][j]
  __shared__ _Float16 Psm[4][16 * 72];    // per-wave P buffer [q][key], pad 64->72

  // ---- load Q A-frags, apply RoPE + fold scale*log2(e) ----
  half8 qf[4];
  {
    int qi = q0 + w * 16 + l15;
    const _Float16* qrow = Qh + ((size_t)(b * S_LEN + qi) * NH + h) * HD;
    const float* crow = cosT + (size_t)qi * HD;
    const float* srow = sinT + (size_t)qi * HD;
    float qv[4][8], cv[4][8], snv[4][8];
#pragma unroll
    for (int kc = 0; kc < 4; ++kc) {
      int d0 = kc * 32 + quad * 8;
      half8 q8 = *(const half8*)(qrow + d0);
#pragma unroll
      for (int j = 0; j < 8; ++j) qv[kc][j] = (float)q8[j];
      *(f32x4*)&cv[kc][0] = *(const f32x4*)(crow + d0);
      *(f32x4*)&cv[kc][4] = *(const f32x4*)(crow + d0 + 4);
      *(f32x4*)&snv[kc][0] = *(const f32x4*)(srow + d0);
      *(f32x4*)&snv[kc][4] = *(const f32x4*)(srow + d0 + 4);
    }
#pragma unroll
    for (int kc = 0; kc < 4; ++kc)
#pragma unroll
      for (int j = 0; j < 8; ++j) {
        float rot = (kc < 2) ? -qv[kc + 2][j] : qv[kc - 2][j];
        qf[kc][j] = (_Float16)((qv[kc][j] * cv[kc][j] + rot * snv[kc][j]) * SL2E);
      }
  }

  f32x4 oacc[8] = {};
  float m_r[4] = {-1e30f, -1e30f, -1e30f, -1e30f};
  float l_r[4] = {0.f, 0.f, 0.f, 0.f};

  int kt_lo = (q0 >= WINDOW) ? ((q0 - (WINDOW - 1)) >> 6) : 0;
  int kt_hi = q0 >> 6;
  for (int kt = kt_lo; kt <= kt_hi; ++kt) {
    int k0 = kt * 64;
    __syncthreads();
    // ---- stage K tile with RoPE: 8 threads/row handle 8 low + 8 high cols ----
    {
      int r = t >> 3, cc = (t & 7) * 8;
#pragma unroll
      for (int p = 0; p < 2; ++p) {
        int krow = p * 32 + r;
        int ks = k0 + krow;
        const _Float16* kr = Kg + ((size_t)(b * S_LEN + ks) * NKV + kvh) * HD;
        const float* crow = cosT + (size_t)ks * HD;
        const float* srow = sinT + (size_t)ks * HD;
        half8 klo = *(const half8*)(kr + cc);
        half8 khi = *(const half8*)(kr + cc + 64);
        float cl[8], sl[8], ch[8], sh[8];
        *(f32x4*)&cl[0] = *(const f32x4*)(crow + cc);
        *(f32x4*)&cl[4] = *(const f32x4*)(crow + cc + 4);
        *(f32x4*)&sl[0] = *(const f32x4*)(srow + cc);
        *(f32x4*)&sl[4] = *(const f32x4*)(srow + cc + 4);
        *(f32x4*)&ch[0] = *(const f32x4*)(crow + cc + 64);
        *(f32x4*)&ch[4] = *(const f32x4*)(crow + cc + 68);
        *(f32x4*)&sh[0] = *(const f32x4*)(srow + cc + 64);
        *(f32x4*)&sh[4] = *(const f32x4*)(srow + cc + 68);
        half8 rlo, rhi;
#pragma unroll
        for (int u = 0; u < 8; ++u) {
          float lo = (float)klo[u], hi = (float)khi[u];
          rlo[u] = (_Float16)(lo * cl[u] - hi * sl[u]);
          rhi[u] = (_Float16)(hi * ch[u] + lo * sh[u]);
        }
        *(half8*)&Ksm[krow * 136 + cc] = rlo;
        *(half8*)&Ksm[krow * 136 + cc + 64] = rhi;
      }
      // ---- stage V into B-frag order (row pairs -> packed b32 writes) ----
      int pairi = t >> 4;
      int cidx = t & 15;
#pragma unroll
      for (int it = 0; it < 2; ++it) {
        int pr = pairi + 16 * it;   // 0..31 row pairs
        int ke = pr * 2;
        const _Float16* v0 = Vg + ((size_t)(b * S_LEN + k0 + ke) * NKV + kvh) * HD;
        const _Float16* v1 = v0 + (size_t)NKV * HD;
        half8 a8 = *(const half8*)(v0 + cidx * 8);
        half8 b8 = *(const half8*)(v1 + cidx * 8);
        int kc2 = ke >> 5;
        int Lb = (ke & 31) >> 3;
        int jj = ke & 7;            // even
#pragma unroll
        for (int u = 0; u < 8; ++u) {
          int d = cidx * 8 + u;
          int nc = d >> 4;
          int L = (d & 15) + 16 * Lb;
          half2_t pk = { a8[u], b8[u] };
          *(half2_t*)&Vsm[(((kc2 * 8 + nc) * 64) + L) * 8 + jj] = pk;
        }
      }
    }
    __syncthreads();

    // ---- S = Q K^T (16 q-rows x 64 keys per wave) ----
    f32x4 sfr[4];
#pragma unroll
    for (int nb = 0; nb < 4; ++nb) {
      f32x4 s = {0.f, 0.f, 0.f, 0.f};
#pragma unroll
      for (int dc = 0; dc < 4; ++dc) {
        half8 bf = *(const half8*)&Ksm[(nb * 16 + l15) * 136 + dc * 32 + quad * 8];
        s = MFMA16(qf[dc], bf, s);
      }
      sfr[nb] = s;
    }

    // ---- mask + online softmax ----
    int qrow0 = q0 + w * 16 + quad * 4;
    float mloc[4] = {-1e30f, -1e30f, -1e30f, -1e30f};
#pragma unroll
    for (int nb = 0; nb < 4; ++nb) {
      int kj = k0 + nb * 16 + l15;
#pragma unroll
      for (int r = 0; r < 4; ++r) {
        int dd = qrow0 + r - kj;
        bool ok = (dd >= 0) && (dd < WINDOW);
        float s = ok ? sfr[nb][r] : -1e30f;
        sfr[nb][r] = s;
        mloc[r] = fmaxf(mloc[r], s);
      }
    }
#pragma unroll
    for (int off = 1; off < 16; off <<= 1)
#pragma unroll
      for (int r = 0; r < 4; ++r)
        mloc[r] = fmaxf(mloc[r], __shfl_xor(mloc[r], off, 64));
    float alpha[4], psum[4];
#pragma unroll
    for (int r = 0; r < 4; ++r) {
      float mnew = fmaxf(m_r[r], mloc[r]);
      alpha[r] = exp2f(m_r[r] - mnew);
      m_r[r] = mnew;
      psum[r] = 0.f;
    }
#pragma unroll
    for (int nb = 0; nb < 4; ++nb) {
#pragma unroll
      for (int r = 0; r < 4; ++r) {
        float p = exp2f(sfr[nb][r] - m_r[r]);
        p = (sfr[nb][r] <= -9e29f) ? 0.f : p;  // fully-masked-row safety
        psum[r] += p;
        Psm[w][(quad * 4 + r) * 72 + nb * 16 + l15] = (_Float16)p;
      }
    }
#pragma unroll
    for (int off = 1; off < 16; off <<= 1)
#pragma unroll
      for (int r = 0; r < 4; ++r)
        psum[r] += __shfl_xor(psum[r], off, 64);
#pragma unroll
    for (int r = 0; r < 4; ++r)
      l_r[r] = l_r[r] * alpha[r] + psum[r];
#pragma unroll
    for (int nc = 0; nc < 8; ++nc)
#pragma unroll
      for (int r = 0; r < 4; ++r)
        oacc[nc][r] *= alpha[r];

    // ---- O += P @ V ----
    half8 af0 = *(const half8*)&Psm[w][l15 * 72 + quad * 8];
    half8 af1 = *(const half8*)&Psm[w][l15 * 72 + 32 + quad * 8];
#pragma unroll
    for (int nc = 0; nc < 8; ++nc) {
      half8 b0 = *(const half8*)&Vsm[((0 * 8 + nc) * 64 + lane) * 8];
      oacc[nc] = MFMA16(af0, b0, oacc[nc]);
      half8 b1 = *(const half8*)&Vsm[((1 * 8 + nc) * 64 + lane) * 8];
      oacc[nc] = MFMA16(af1, b1, oacc[nc]);
    }
  }

  // ---- epilogue: normalize, store fp16 ----
#pragma unroll
  for (int r = 0; r < 4; ++r) {
    int qi = q0 + w * 16 + quad * 4 + r;
    float inv = 1.0f / l_r[r];
    _Float16* orow = Oh + (size_t)(b * S_LEN + qi) * EMB + h * HD;
#pragma unroll
    for (int nc = 0; nc < 8; ++nc)
      orow[nc * 16 + l15] = (_Float16)(oacc[nc][r] * inv);
  }
}

// ---------------------------------------------------------------------------
// Output projection: out = Oh @ Wo^T, A fp16 [4096,2048], Wo fp32, out fp32.
// ---------------------------------------------------------------------------
__global__ __launch_bounds__(256)
void out_gemm(const _Float16* __restrict__ A, const float* __restrict__ Wo,
              float* __restrict__ out) {
  __shared__ _Float16 Asm[128 * 72];
  __shared__ _Float16 Bsm[128 * 72];
  const int K = EMB;
  int m0 = blockIdx.y * 128, n0 = blockIdx.x * 128;
  int t = threadIdx.x, lane = t & 63, w = t >> 6;
  int l15 = lane & 15, quad = lane >> 4;
  int wm = (w >> 1) * 64, wn = (w & 1) * 64;
  f32x4 acc[4][4] = {};
  int ar = t >> 3, ac = (t & 7) * 8;
  int br = t >> 4, bc = (t & 15) * 4;
  for (int kt = 0; kt < K; kt += 64) {
    __syncthreads();
#pragma unroll
    for (int p = 0; p < 4; ++p) {
      int row = p * 32 + ar;
      *(half8*)&Asm[row * 72 + ac] = *(const half8*)(A + (size_t)(m0 + row) * K + kt + ac);
    }
#pragma unroll
    for (int p = 0; p < 8; ++p) {
      int row = p * 16 + br;
      f32x4 vb = *(const f32x4*)(Wo + (size_t)(n0 + row) * K + kt + bc);
      half4_t hb = { (_Float16)vb[0], (_Float16)vb[1], (_Float16)vb[2], (_Float16)vb[3] };
      *(half4_t*)&Bsm[row * 72 + bc] = hb;
    }
    __syncthreads();
#pragma unroll
    for (int kc = 0; kc < 2; ++kc) {
      half8 af[4], bf[4];
#pragma unroll
      for (int i = 0; i < 4; ++i)
        af[i] = *(const half8*)&Asm[(wm + i * 16 + l15) * 72 + kc * 32 + quad * 8];
#pragma unroll
      for (int i = 0; i < 4; ++i)
        bf[i] = *(const half8*)&Bsm[(wn + i * 16 + l15) * 72 + kc * 32 + quad * 8];
#pragma unroll
      for (int mi = 0; mi < 4; ++mi)
#pragma unroll
        for (int ni = 0; ni < 4; ++ni)
          acc[mi][ni] = MFMA16(af[mi], bf[ni], acc[mi][ni]);
    }
  }
#pragma unroll
  for (int mi = 0; mi < 4; ++mi)
#pragma unroll
    for (int ni = 0; ni < 4; ++ni)
#pragma unroll
      for (int r = 0; r < 4; ++r) {
        int row = m0 + wm + mi * 16 + quad * 4 + r;
        int col = n0 + wn + ni * 16 + l15;
        out[(size_t)row * EMB + col] = acc[mi][ni][r];
      }
}

extern "C" void kernel_launch(void* const* d_in, const int* in_sizes, int n_in,
                              void* d_out, int out_size, void* d_ws, size_t ws_size,
                              hipStream_t stream) {
  const float* x    = (const float*)d_in[0];
  const float* cosT = (const float*)d_in[1];
  const float* sinT = (const float*)d_in[2];
  const float* Wq   = (const float*)d_in[3];
  const float* Wk   = (const float*)d_in[4];
  const float* Wv   = (const float*)d_in[5];
  const float* Wo   = (const float*)d_in[6];
  float* out = (float*)d_out;

  char* ws = (char*)d_ws;
  _Float16* Qh   = (_Float16*)(ws);                       // 4096*2048*2 = 16 MiB
  _Float16* Kh16 = (_Float16*)(ws + 16777216);            // 4096*512*2  =  4 MiB
  _Float16* Vh16 = (_Float16*)(ws + 16777216 + 4194304);  // 4 MiB
  _Float16* Oh   = (_Float16*)(ws + 16777216 + 8388608);  // 16 MiB  (total 40 MiB)

  qkv_gemm<<<dim3(24, 32), 256, 0, stream>>>(x, Wq, Wk, Wv, Qh, Kh16, Vh16);
  attn_fused<<<dim3(32, NH, BATCH), 256, 0, stream>>>(Qh, Kh16, Vh16, cosT, sinT, Oh);
  out_gemm<<<dim3(16, 32), 256, 0, stream>>>(Oh, Wo, out);
}